// Round 3
// baseline (3308.909 us; speedup 1.0000x reference)
//
#include <hip/hip_runtime.h>
#include <cstdint>
#include <cstddef>

#define NN   50000
#define NE   400000
#define FDIM 256
#define HDIM 512
#define CDIM 3
#define NBLK 6

typedef __attribute__((ext_vector_type(4))) float f4;
typedef __attribute__((ext_vector_type(4))) float f32x4;
typedef _Float16 half8 __attribute__((ext_vector_type(8)));
typedef _Float16 half4 __attribute__((ext_vector_type(4)));

template <typename T>
__device__ inline void nt_store(T* p, T v) { __builtin_nontemporal_store(v, p); }

// async global->LDS 16B copy (global_load_lds_dwordx4). LDS dest must be
// wave-uniform base + lane*16 (HW constraint); our staging index is linear in
// lane so this holds. Global src is per-lane (allowed) -> source-side swizzle.
typedef __attribute__((address_space(1))) const void glob_void;
typedef __attribute__((address_space(3))) void lds_void;
__device__ __forceinline__ void async16(void* lds, const void* g) {
  __builtin_amdgcn_global_load_lds((glob_void*)g, (lds_void*)lds, 16, 0, 0);
}

// ---------------- setup kernels ----------------

__global__ __launch_bounds__(256) void k_zero_i32(int* p, int n) {
  int i = blockIdx.x * 256 + threadIdx.x;
  if (i < n) p[i] = 0;
}

__global__ __launch_bounds__(256) void k_hist(const int* __restrict__ dst, int* __restrict__ cnt) {
  int e = blockIdx.x * 256 + threadIdx.x;
  if (e < NE) {
    int d = dst[e];
    if ((unsigned)d < (unsigned)NN) atomicAdd(&cnt[d], 1);
  }
}

__global__ __launch_bounds__(256) void k_dinv(const int* __restrict__ cnt, float* __restrict__ dinv) {
  int i = blockIdx.x * 256 + threadIdx.x;
  if (i < NN) dinv[i] = rsqrtf((float)cnt[i] + 1.0f);
}

// single-block exclusive scan of cnt[NN] -> row_start[NN+1]
__global__ __launch_bounds__(1024) void k_scan(const int* __restrict__ cnt, int* __restrict__ row_start) {
  __shared__ int wsum[16];
  __shared__ int carry_s;
  int tid = threadIdx.x, lane = tid & 63, wid = tid >> 6;
  if (tid == 0) carry_s = 0;
  __syncthreads();
  for (int base = 0; base < NN; base += 1024) {
    int i = base + tid;
    int v = (i < NN) ? cnt[i] : 0;
    int incl = v;
#pragma unroll
    for (int off = 1; off < 64; off <<= 1) {
      int t = __shfl_up(incl, off);
      if (lane >= off) incl += t;
    }
    if (lane == 63) wsum[wid] = incl;
    __syncthreads();
    int woff = 0;
    for (int w = 0; w < wid; ++w) woff += wsum[w];
    int excl = carry_s + woff + (incl - v);
    if (i < NN) row_start[i] = excl;
    __syncthreads();
    if (tid == 1023) carry_s = excl + v;
    __syncthreads();
  }
  if (threadIdx.x == 0) row_start[NN] = carry_s;
}

__global__ __launch_bounds__(256) void k_fill(const int* __restrict__ src, const int* __restrict__ dst,
    const int* __restrict__ row_start, int* __restrict__ fill,
    const float* __restrict__ dinv, int* __restrict__ csr_src, float* __restrict__ csr_coef) {
  int e = blockIdx.x * 256 + threadIdx.x;
  if (e >= NE) return;
  int s = src[e], d = dst[e];
  if ((unsigned)s >= (unsigned)NN || (unsigned)d >= (unsigned)NN) return;
  int pos = row_start[d] + atomicAdd(&fill[d], 1);
  csr_src[pos] = s;
  csr_coef[pos] = dinv[s] * dinv[d];
}

// ---------------- conversion kernels ----------------

// x [N,256] fp32 -> hi/lo fp16 (no relu, no transpose)
__global__ __launch_bounds__(256) void k_cvt_x(const float* __restrict__ x,
    _Float16* __restrict__ xhi, _Float16* __restrict__ xlo, int n4) {
  int i = blockIdx.x * 256 + threadIdx.x;
  if (i >= n4) return;
  f4 v = ((const f4*)x)[i];
  half4 h, l;
#pragma unroll
  for (int c = 0; c < 4; ++c) {
    float vv = v[c];
    _Float16 hh = (_Float16)vv;
    h[c] = hh;
    l[c] = (_Float16)(vv - (float)hh);
  }
  ((half4*)xhi)[i] = h;
  ((half4*)xlo)[i] = l;
}

// W [K,N] fp32 -> transposed hi/lo fp16 [N,K]  (z = matrix index)
__global__ __launch_bounds__(256) void k_cvt_wt(const float* __restrict__ W,
    _Float16* __restrict__ Whi, _Float16* __restrict__ Wlo, int K, int N) {
  __shared__ float tile[32][33];
  int l = blockIdx.z;
  const float* Wl = W + (size_t)l * K * N;
  _Float16* Oh = Whi + (size_t)l * K * N;
  _Float16* Ol = Wlo + (size_t)l * K * N;
  int k0 = blockIdx.x * 32, n0 = blockIdx.y * 32;
  int tx = threadIdx.x & 31, ty = threadIdx.x >> 5;
#pragma unroll
  for (int p = 0; p < 4; ++p)
    tile[ty + 8 * p][tx] = Wl[(size_t)(k0 + ty + 8 * p) * N + n0 + tx];
  __syncthreads();
#pragma unroll
  for (int p = 0; p < 4; ++p) {
    int n = n0 + ty + 8 * p, k = k0 + tx;
    float v = tile[tx][ty + 8 * p];
    _Float16 hi = (_Float16)v;
    Oh[(size_t)n * K + k] = hi;
    Ol[(size_t)n * K + k] = (_Float16)(v - (float)hi);
  }
}

// ---------------- MFMA GEMM: C[M,512] = (Ahi+Alo)[M,K] @ (Bhi+Blo)^T ----------------
// A: [M,K] fp16 hi/lo; B: [N,K] fp16 hi/lo (pre-transposed, k-contiguous)
// fp32-accurate via 3-term split: ah*bh + ah*bl + al*bh
// Staging: global_load_lds width=16 into LINEAR LDS [128][32] (no pad -- DMA
// dest must be lane-linear). Bank conflicts on the b128 fragment reads are
// avoided with a chunk XOR swizzle applied on the GLOBAL SOURCE address:
//   LDS slot (row, j) holds global 16B-chunk (row, j ^ ((row>>1)&3))
// and the fragment read uses j = quad ^ ((row>>1)&3). Within each 8-lane
// phase of a ds_read_b128, the 8 lanes then hit 8 distinct 16B bank slots.
// A-tile rows >= M stage row M-1 instead (clamped; duplicate data is dead --
// output rows >= M are never stored). Keeps all reads in-bounds.

__global__ __launch_bounds__(256) void k_gemm16(
    const _Float16* __restrict__ Ahi, const _Float16* __restrict__ Alo,
    const _Float16* __restrict__ Bhi, const _Float16* __restrict__ Blo,
    float* __restrict__ C, int M, int K) {
  const int nrb = (M + 127) >> 7;         // row blocks (391)
  const int rpx = (nrb + 7) >> 3;         // row blocks per XCD (49)
  const int f = blockIdx.x;
  const int q8 = f & 7, s = f >> 3;
  const int rb = q8 * rpx + (s >> 2);
  const int cb = s & 3;
  if (rb >= nrb) return;
  const int row0 = rb * 128, col0 = cb * 128;

  __shared__ _Float16 As[2][128][32];
  __shared__ _Float16 Bs[2][128][32];
  const int tid = threadIdx.x;
  const int lane = tid & 63, wave = tid >> 6;
  const int wm = wave & 1, wn = wave >> 1;
  const int quad = lane >> 4, r = lane & 15;

  // staging: thread handles chunk-slots c and c+256; slot c = (row c>>2, j c&3)
  const int rr0 = tid >> 2, jc0 = tid & 3;
  const int rr1 = (tid + 256) >> 2, jc1 = tid & 3;  // (c+256)&3 == c&3
  const int gj0 = jc0 ^ ((rr0 >> 1) & 3);
  const int gj1 = jc1 ^ ((rr1 >> 1) & 3);
  const int ar0 = min(row0 + rr0, M - 1);   // clamp A rows (in-bounds)
  const int ar1 = min(row0 + rr1, M - 1);

  f32x4 acc[4][4];
#pragma unroll
  for (int i = 0; i < 4; ++i)
#pragma unroll
    for (int j = 0; j < 4; ++j) acc[i][j] = (f32x4){0.f, 0.f, 0.f, 0.f};

  for (int k0 = 0; k0 < K; k0 += 32) {
    // stage A & B tiles (hi + lo): 8 async 16B DMAs per thread
    {
      size_t ga0 = (size_t)ar0 * K + k0 + gj0 * 8;
      size_t gb0 = (size_t)(col0 + rr0) * K + k0 + gj0 * 8;
      size_t ga1 = (size_t)ar1 * K + k0 + gj1 * 8;
      size_t gb1 = (size_t)(col0 + rr1) * K + k0 + gj1 * 8;
      async16(&As[0][rr0][jc0 * 8], Ahi + ga0);
      async16(&As[1][rr0][jc0 * 8], Alo + ga0);
      async16(&Bs[0][rr0][jc0 * 8], Bhi + gb0);
      async16(&Bs[1][rr0][jc0 * 8], Blo + gb0);
      async16(&As[0][rr1][jc1 * 8], Ahi + ga1);
      async16(&As[1][rr1][jc1 * 8], Alo + ga1);
      async16(&Bs[0][rr1][jc1 * 8], Bhi + gb1);
      async16(&Bs[1][rr1][jc1 * 8], Blo + gb1);
    }
    __syncthreads();  // compiler inserts vmcnt(0) before barrier

    half8 ah[4], al[4], bh[4], bl[4];
#pragma unroll
    for (int mi = 0; mi < 4; ++mi) {
      int mrow = wm * 64 + mi * 16 + r;
      int js = (quad ^ ((mrow >> 1) & 3)) * 8;
      ah[mi] = *(const half8*)&As[0][mrow][js];
      al[mi] = *(const half8*)&As[1][mrow][js];
    }
#pragma unroll
    for (int ni = 0; ni < 4; ++ni) {
      int nrow = wn * 64 + ni * 16 + r;
      int js = (quad ^ ((nrow >> 1) & 3)) * 8;
      bh[ni] = *(const half8*)&Bs[0][nrow][js];
      bl[ni] = *(const half8*)&Bs[1][nrow][js];
    }
#pragma unroll
    for (int mi = 0; mi < 4; ++mi)
#pragma unroll
      for (int ni = 0; ni < 4; ++ni) {
        acc[mi][ni] = __builtin_amdgcn_mfma_f32_16x16x32_f16(ah[mi], bh[ni], acc[mi][ni], 0, 0, 0);
        acc[mi][ni] = __builtin_amdgcn_mfma_f32_16x16x32_f16(ah[mi], bl[ni], acc[mi][ni], 0, 0, 0);
        acc[mi][ni] = __builtin_amdgcn_mfma_f32_16x16x32_f16(al[mi], bh[ni], acc[mi][ni], 0, 0, 0);
      }
    __syncthreads();
  }

  // epilogue: C/D layout col=lane&15, row=quad*4+reg. PLAIN stores: letting L2
  // buffer Y (instead of nt write-through) measured faster overall (R0->R1).
#pragma unroll
  for (int mi = 0; mi < 4; ++mi)
#pragma unroll
    for (int reg = 0; reg < 4; ++reg) {
      int grow = row0 + wm * 64 + mi * 16 + quad * 4 + reg;
      if (grow < M) {
#pragma unroll
        for (int ni = 0; ni < 4; ++ni)
          C[(size_t)grow * HDIM + col0 + wn * 64 + ni * 16 + r] = acc[mi][ni][reg];
      }
    }
}

// ---------------- CSR aggregation (wave-per-node, full 512-feat row) ----------------
// xrelu = relu(b + dinv_i^2*h_i + sum coef*h_src); emit fp16 hi/lo (+ optional fp32)
// Fabric-bound at ~4.3 TB/s beyond-L2 (R0/R1 both measured it); stores are nt
// (16B) so X-writes don't allocate L2 lines and evict gather lines (R1's plain
// stores cost +18 MB FETCH vs R0's nt).

__global__ __launch_bounds__(256) void k_agg(const float* __restrict__ h,
    _Float16* __restrict__ xhi, _Float16* __restrict__ xlo, float* __restrict__ xf,
    const int* __restrict__ row_start, const int* __restrict__ csr_src,
    const float* __restrict__ csr_coef, const float* __restrict__ dinv,
    const float* __restrict__ bias) {
  int wid = threadIdx.x >> 6, lane = threadIdx.x & 63;
  int i = blockIdx.x * 4 + wid;
  if (i >= NN) return;
  int c = lane * 8;  // feats [c, c+8)
  float di = dinv[i];
  float d2 = di * di;
  const f4* hrow = (const f4*)(h + (size_t)i * HDIM + c);
  f4 a0 = hrow[0] * d2, b0 = hrow[1] * d2;
  f4 z = {0.f, 0.f, 0.f, 0.f};
  f4 a1 = z, b1 = z, a2 = z, b2 = z, a3 = z, b3 = z;
  int e0 = row_start[i], e1 = row_start[i + 1];
  int e = e0;
  // 4 independent row-gathers (8 dwordx4 loads) in flight per wave
  for (; e + 4 <= e1; e += 4) {
    int s0 = csr_src[e], s1 = csr_src[e + 1], s2 = csr_src[e + 2], s3 = csr_src[e + 3];
    float c0 = csr_coef[e], c1 = csr_coef[e + 1], c2 = csr_coef[e + 2], c3 = csr_coef[e + 3];
    const f4* r0 = (const f4*)(h + (size_t)s0 * HDIM + c);
    const f4* r1 = (const f4*)(h + (size_t)s1 * HDIM + c);
    const f4* r2 = (const f4*)(h + (size_t)s2 * HDIM + c);
    const f4* r3 = (const f4*)(h + (size_t)s3 * HDIM + c);
    f4 p0 = r0[0], q0 = r0[1];
    f4 p1 = r1[0], q1 = r1[1];
    f4 p2 = r2[0], q2 = r2[1];
    f4 p3 = r3[0], q3 = r3[1];
    a0 += p0 * c0; b0 += q0 * c0;
    a1 += p1 * c1; b1 += q1 * c1;
    a2 += p2 * c2; b2 += q2 * c2;
    a3 += p3 * c3; b3 += q3 * c3;
  }
  for (; e < e1; ++e) {
    int s = csr_src[e];
    float cf = csr_coef[e];
    const f4* r = (const f4*)(h + (size_t)s * HDIM + c);
    a0 += r[0] * cf;
    b0 += r[1] * cf;
  }
  f4 accA = (a0 + a1) + (a2 + a3);
  f4 accB = (b0 + b1) + (b2 + b3);
  accA += *(const f4*)(bias + c);
  accB += *(const f4*)(bias + c + 4);
#pragma unroll
  for (int q = 0; q < 4; ++q) {
    accA[q] = fmaxf(accA[q], 0.f);
    accB[q] = fmaxf(accB[q], 0.f);
  }
  half8 hh, ll;
#pragma unroll
  for (int q = 0; q < 4; ++q) {
    _Float16 hv = (_Float16)accA[q];
    hh[q] = hv;
    ll[q] = (_Float16)(accA[q] - (float)hv);
    _Float16 hv2 = (_Float16)accB[q];
    hh[q + 4] = hv2;
    ll[q + 4] = (_Float16)(accB[q] - (float)hv2);
  }
  nt_store((half8*)(xhi + (size_t)i * HDIM + c), hh);
  nt_store((half8*)(xlo + (size_t)i * HDIM + c), ll);
  if (xf) {
    f4* xo = (f4*)(xf + (size_t)i * HDIM + c);
    nt_store(&xo[0], accA);
    nt_store(&xo[1], accB);
  }
}

// final conv: h3[N,3] = X[N,512] @ W1[512,3]; one wave per node
__global__ __launch_bounds__(256) void k_gemm3(const float* __restrict__ X, const float* __restrict__ W1,
    float* __restrict__ h3) {
  int wid = threadIdx.x >> 6, lane = threadIdx.x & 63;
  int i = blockIdx.x * 4 + wid;
  if (i >= NN) return;
  const float* xi = X + (size_t)i * HDIM;
  float a0 = 0.f, a1 = 0.f, a2 = 0.f;
#pragma unroll
  for (int t = 0; t < HDIM / 64; ++t) {
    int k = t * 64 + lane;
    float v = xi[k];
    a0 = fmaf(v, W1[k * 3 + 0], a0);
    a1 = fmaf(v, W1[k * 3 + 1], a1);
    a2 = fmaf(v, W1[k * 3 + 2], a2);
  }
#pragma unroll
  for (int off = 32; off > 0; off >>= 1) {
    a0 += __shfl_down(a0, off);
    a1 += __shfl_down(a1, off);
    a2 += __shfl_down(a2, off);
  }
  if (lane == 0) {
    h3[(size_t)i * 3 + 0] = a0;
    h3[(size_t)i * 3 + 1] = a1;
    h3[(size_t)i * 3 + 2] = a2;
  }
}

__global__ __launch_bounds__(256) void k_agg3(const float* __restrict__ h3, float* __restrict__ out,
    const int* __restrict__ row_start, const int* __restrict__ csr_src,
    const float* __restrict__ csr_coef, const float* __restrict__ dinv,
    const float* __restrict__ b1) {
  int i = blockIdx.x * 256 + threadIdx.x;
  if (i >= NN) return;
  float d2 = dinv[i] * dinv[i];
  float o0 = h3[(size_t)i * 3 + 0] * d2;
  float o1 = h3[(size_t)i * 3 + 1] * d2;
  float o2 = h3[(size_t)i * 3 + 2] * d2;
  int e0 = row_start[i], e1 = row_start[i + 1];
  for (int e = e0; e < e1; ++e) {
    int s = csr_src[e];
    float c = csr_coef[e];
    o0 = fmaf(c, h3[(size_t)s * 3 + 0], o0);
    o1 = fmaf(c, h3[(size_t)s * 3 + 1], o1);
    o2 = fmaf(c, h3[(size_t)s * 3 + 2], o2);
  }
  out[(size_t)i * 3 + 0] = o0 + b1[0];
  out[(size_t)i * 3 + 1] = o1 + b1[1];
  out[(size_t)i * 3 + 2] = o2 + b1[2];
}

// ---------------- launch ----------------

extern "C" void kernel_launch(void* const* d_in, const int* in_sizes, int n_in,
                              void* d_out, int out_size, void* d_ws, size_t ws_size,
                              hipStream_t stream) {
  const float* x  = (const float*)d_in[0];
  const int*   ei = (const int*)d_in[1];
  const float* W0 = (const float*)d_in[2];
  const float* b0 = (const float*)d_in[3];
  const float* Wr = (const float*)d_in[4];
  const float* br = (const float*)d_in[5];
  const float* W1 = (const float*)d_in[6];
  const float* b1 = (const float*)d_in[7];
  float* out = (float*)d_out;
  float* X = out + (size_t)NN * CDIM;  // final relu'd state [NN, HDIM] == output 1

  char* ws = (char*)d_ws;
  size_t off = 0;
  auto alloc = [&](size_t bytes) -> void* {
    void* p = ws + off;
    off = (off + bytes + 255) & ~(size_t)255;
    return p;
  };
  float*     Y      = (float*)alloc((size_t)NN * HDIM * 4);        // 102.4 MB
  _Float16*  Xhi    = (_Float16*)alloc((size_t)NN * HDIM * 2);     // 51.2 MB
  _Float16*  Xlo    = (_Float16*)alloc((size_t)NN * HDIM * 2);     // 51.2 MB
  _Float16*  W0thi  = (_Float16*)alloc((size_t)FDIM * HDIM * 2);
  _Float16*  W0tlo  = (_Float16*)alloc((size_t)FDIM * HDIM * 2);
  _Float16*  Wrthi  = (_Float16*)alloc((size_t)NBLK * 2 * HDIM * HDIM * 2);
  _Float16*  Wrtlo  = (_Float16*)alloc((size_t)NBLK * 2 * HDIM * HDIM * 2);
  float*     csr_coef = (float*)alloc((size_t)NE * 4);
  float*     dinv     = (float*)alloc((size_t)NN * 4);
  float*     h3       = (float*)alloc((size_t)NN * CDIM * 4);
  int*       cnt      = (int*)alloc((size_t)NN * 4);
  int*       fill     = (int*)alloc((size_t)NN * 4);
  int*       row_start= (int*)alloc((size_t)(NN + 1) * 4);
  int*       csr_src  = (int*)alloc((size_t)NE * 4);

  const int* src = ei;
  const int* dst = ei + NE;

  // ---- setup (once per call; reused by all 14 layers) ----
  k_zero_i32<<<(NN + 255) / 256, 256, 0, stream>>>(cnt, NN);
  k_zero_i32<<<(NN + 255) / 256, 256, 0, stream>>>(fill, NN);
  k_hist<<<(NE + 255) / 256, 256, 0, stream>>>(dst, cnt);
  k_dinv<<<(NN + 255) / 256, 256, 0, stream>>>(cnt, dinv);
  k_scan<<<1, 1024, 0, stream>>>(cnt, row_start);
  k_fill<<<(NE + 255) / 256, 256, 0, stream>>>(src, dst, row_start, fill, dinv, csr_src, csr_coef);

  // weight + input conversion (hi/lo fp16, weights transposed to [N][K])
  k_cvt_x<<<(NN * FDIM / 4 + 255) / 256, 256, 0, stream>>>(x, Xhi, Xlo, NN * FDIM / 4);
  {
    dim3 g0(FDIM / 32, HDIM / 32, 1);
    k_cvt_wt<<<g0, 256, 0, stream>>>(W0, W0thi, W0tlo, FDIM, HDIM);
    dim3 gr(HDIM / 32, HDIM / 32, NBLK * 2);
    k_cvt_wt<<<gr, 256, 0, stream>>>(Wr, Wrthi, Wrtlo, HDIM, HDIM);
  }

  const int nrb = (NN + 127) / 128;          // 391 row blocks
  const int rpx = (nrb + 7) / 8;             // 49 per XCD
  const int gemm_blocks = 8 * rpx * 4;       // 1568 (XCD-swizzled 1D grid)
  dim3 agg_grid((NN + 3) / 4);               // wave per node, full 512 feats

  // conv0: (x0 hi/lo live in the head of Xhi/Xlo; consumed before agg overwrites)
  k_gemm16<<<gemm_blocks, 256, 0, stream>>>(Xhi, Xlo, W0thi, W0tlo, Y, NN, FDIM);
  k_agg<<<agg_grid, 256, 0, stream>>>(Y, Xhi, Xlo, nullptr, row_start, csr_src, csr_coef, dinv, b0);

  // 6 residual blocks x 2 convs, all H->H
  for (int ib = 0; ib < NBLK; ++ib) {
    for (int j = 0; j < 2; ++j) {
      int li = ib * 2 + j;
      const _Float16* Wh = Wrthi + (size_t)li * HDIM * HDIM;
      const _Float16* Wl = Wrtlo + (size_t)li * HDIM * HDIM;
      const float* bb = br + (size_t)li * HDIM;
      bool last = (ib == NBLK - 1) && (j == 1);
      k_gemm16<<<gemm_blocks, 256, 0, stream>>>(Xhi, Xlo, Wh, Wl, Y, NN, HDIM);
      k_agg<<<agg_grid, 256, 0, stream>>>(Y, Xhi, Xlo, last ? X : nullptr,
                                          row_start, csr_src, csr_coef, dinv, bb);
    }
  }

  // final conv: X (relu'd, fp32) @ W1 -> out[N,3]
  k_gemm3<<<(NN + 3) / 4, 256, 0, stream>>>(X, W1, h3);
  k_agg3<<<(NN + 255) / 256, 256, 0, stream>>>(h3, out, row_start, csr_src, csr_coef, dinv, b1);
}

// Round 4
// 3128.143 us; speedup vs baseline: 1.0578x; 1.0578x over previous
//
#include <hip/hip_runtime.h>
#include <cstdint>
#include <cstddef>

#define NN   50000
#define NE   400000
#define FDIM 256
#define HDIM 512
#define CDIM 3
#define NBLK 6

typedef __attribute__((ext_vector_type(4))) float f4;
typedef __attribute__((ext_vector_type(4))) float f32x4;
typedef _Float16 half8 __attribute__((ext_vector_type(8)));
typedef _Float16 half4 __attribute__((ext_vector_type(4)));

template <typename T>
__device__ inline void nt_store(T* p, T v) { __builtin_nontemporal_store(v, p); }

// async global->LDS 16B copy (global_load_lds_dwordx4). LDS dest must be
// wave-uniform base + lane*16 (HW constraint); our staging index is linear in
// lane so this holds. Global src is per-lane (allowed) -> source-side swizzle.
typedef __attribute__((address_space(1))) const void glob_void;
typedef __attribute__((address_space(3))) void lds_void;
__device__ __forceinline__ void async16(void* lds, const void* g) {
  __builtin_amdgcn_global_load_lds((glob_void*)g, (lds_void*)lds, 16, 0, 0);
}

// ---------------- setup kernels ----------------

__global__ __launch_bounds__(256) void k_zero_i32(int* p, int n) {
  int i = blockIdx.x * 256 + threadIdx.x;
  if (i < n) p[i] = 0;
}

__global__ __launch_bounds__(256) void k_hist(const int* __restrict__ dst, int* __restrict__ cnt) {
  int e = blockIdx.x * 256 + threadIdx.x;
  if (e < NE) {
    int d = dst[e];
    if ((unsigned)d < (unsigned)NN) atomicAdd(&cnt[d], 1);
  }
}

__global__ __launch_bounds__(256) void k_dinv(const int* __restrict__ cnt, float* __restrict__ dinv) {
  int i = blockIdx.x * 256 + threadIdx.x;
  if (i < NN) dinv[i] = rsqrtf((float)cnt[i] + 1.0f);
}

// single-block exclusive scan of cnt[NN] -> row_start[NN+1]
__global__ __launch_bounds__(1024) void k_scan(const int* __restrict__ cnt, int* __restrict__ row_start) {
  __shared__ int wsum[16];
  __shared__ int carry_s;
  int tid = threadIdx.x, lane = tid & 63, wid = tid >> 6;
  if (tid == 0) carry_s = 0;
  __syncthreads();
  for (int base = 0; base < NN; base += 1024) {
    int i = base + tid;
    int v = (i < NN) ? cnt[i] : 0;
    int incl = v;
#pragma unroll
    for (int off = 1; off < 64; off <<= 1) {
      int t = __shfl_up(incl, off);
      if (lane >= off) incl += t;
    }
    if (lane == 63) wsum[wid] = incl;
    __syncthreads();
    int woff = 0;
    for (int w = 0; w < wid; ++w) woff += wsum[w];
    int excl = carry_s + woff + (incl - v);
    if (i < NN) row_start[i] = excl;
    __syncthreads();
    if (tid == 1023) carry_s = excl + v;
    __syncthreads();
  }
  if (threadIdx.x == 0) row_start[NN] = carry_s;
}

__global__ __launch_bounds__(256) void k_fill(const int* __restrict__ src, const int* __restrict__ dst,
    const int* __restrict__ row_start, int* __restrict__ fill,
    const float* __restrict__ dinv, int* __restrict__ csr_src, float* __restrict__ csr_coef) {
  int e = blockIdx.x * 256 + threadIdx.x;
  if (e >= NE) return;
  int s = src[e], d = dst[e];
  if ((unsigned)s >= (unsigned)NN || (unsigned)d >= (unsigned)NN) return;
  int pos = row_start[d] + atomicAdd(&fill[d], 1);
  csr_src[pos] = s;
  csr_coef[pos] = dinv[s] * dinv[d];
}

// ---------------- conversion kernels ----------------

// x [N,256] fp32 -> hi/lo fp16 (no relu, no transpose)
__global__ __launch_bounds__(256) void k_cvt_x(const float* __restrict__ x,
    _Float16* __restrict__ xhi, _Float16* __restrict__ xlo, int n4) {
  int i = blockIdx.x * 256 + threadIdx.x;
  if (i >= n4) return;
  f4 v = ((const f4*)x)[i];
  half4 h, l;
#pragma unroll
  for (int c = 0; c < 4; ++c) {
    float vv = v[c];
    _Float16 hh = (_Float16)vv;
    h[c] = hh;
    l[c] = (_Float16)(vv - (float)hh);
  }
  ((half4*)xhi)[i] = h;
  ((half4*)xlo)[i] = l;
}

// W [K,N] fp32 -> transposed hi/lo fp16 [N,K]  (z = matrix index)
__global__ __launch_bounds__(256) void k_cvt_wt(const float* __restrict__ W,
    _Float16* __restrict__ Whi, _Float16* __restrict__ Wlo, int K, int N) {
  __shared__ float tile[32][33];
  int l = blockIdx.z;
  const float* Wl = W + (size_t)l * K * N;
  _Float16* Oh = Whi + (size_t)l * K * N;
  _Float16* Ol = Wlo + (size_t)l * K * N;
  int k0 = blockIdx.x * 32, n0 = blockIdx.y * 32;
  int tx = threadIdx.x & 31, ty = threadIdx.x >> 5;
#pragma unroll
  for (int p = 0; p < 4; ++p)
    tile[ty + 8 * p][tx] = Wl[(size_t)(k0 + ty + 8 * p) * N + n0 + tx];
  __syncthreads();
#pragma unroll
  for (int p = 0; p < 4; ++p) {
    int n = n0 + ty + 8 * p, k = k0 + tx;
    float v = tile[tx][ty + 8 * p];
    _Float16 hi = (_Float16)v;
    Oh[(size_t)n * K + k] = hi;
    Ol[(size_t)n * K + k] = (_Float16)(v - (float)hi);
  }
}

// ---------------- MFMA GEMM: C[M,512] = (Ahi+Alo)[M,K] @ (Bhi+Blo)^T ----------------
// A: [M,K] fp16 hi/lo; B: [N,K] fp16 hi/lo (pre-transposed, k-contiguous)
// fp32-accurate via 3-term split: ah*bh + ah*bl + al*bh
// Staging: global_load_lds width=16, 2-PHASE DOUBLE BUFFER (T3-min):
//   prologue: STAGE(buf0) ; vmcnt(0)+barrier
//   iter t:   STAGE(buf^1, t+1) ; ds_read buf ; MFMA ; barrier (drains vmcnt)
// -> next-tile DMA latency hides under current tile's ds_read+MFMA; the only
// vmcnt(0) drain sits AFTER the MFMA block. Race-free: buffer being staged was
// last read before the PREVIOUS barrier.
// Bank conflicts on b128 fragment reads avoided by chunk XOR swizzle applied
// on the GLOBAL SOURCE address: LDS slot (row,j) holds chunk (row, j^((row>>1)&3));
// fragment read uses the same XOR. DMA dest stays lane-linear (HW constraint).
// A-tile rows >= M stage row M-1 (clamped; dead data, out rows >=M not stored).

__global__ __launch_bounds__(256) void k_gemm16(
    const _Float16* __restrict__ Ahi, const _Float16* __restrict__ Alo,
    const _Float16* __restrict__ Bhi, const _Float16* __restrict__ Blo,
    float* __restrict__ C, int M, int K) {
  const int nrb = (M + 127) >> 7;         // row blocks (391)
  const int rpx = (nrb + 7) >> 3;         // row blocks per XCD (49)
  const int f = blockIdx.x;
  const int q8 = f & 7, s = f >> 3;
  const int rb = q8 * rpx + (s >> 2);
  const int cb = s & 3;
  if (rb >= nrb) return;
  const int row0 = rb * 128, col0 = cb * 128;

  __shared__ _Float16 As[2][2][128][32];   // [buf][hi/lo][row][k]
  __shared__ _Float16 Bs[2][2][128][32];
  const int tid = threadIdx.x;
  const int lane = tid & 63, wave = tid >> 6;
  const int wm = wave & 1, wn = wave >> 1;
  const int quad = lane >> 4, r = lane & 15;

  // staging: thread handles rows rr0 and rr0+64, chunk jc (16B each)
  const int rr0 = tid >> 2, jc = tid & 3;
  const int rr1 = rr0 + 64;
  const int gj0 = jc ^ ((rr0 >> 1) & 3);
  const int gj1 = jc ^ ((rr1 >> 1) & 3);
  const int ar0 = min(row0 + rr0, M - 1);   // clamp A rows (in-bounds)
  const int ar1 = min(row0 + rr1, M - 1);
  const int br0 = col0 + rr0, br1 = col0 + rr1;

  f32x4 acc[4][4];
#pragma unroll
  for (int i = 0; i < 4; ++i)
#pragma unroll
    for (int j = 0; j < 4; ++j) acc[i][j] = (f32x4){0.f, 0.f, 0.f, 0.f};

  auto stage = [&](int b, int k0) {
    size_t ga0 = (size_t)ar0 * K + k0 + gj0 * 8;
    size_t gb0 = (size_t)br0 * K + k0 + gj0 * 8;
    size_t ga1 = (size_t)ar1 * K + k0 + gj1 * 8;
    size_t gb1 = (size_t)br1 * K + k0 + gj1 * 8;
    async16(&As[b][0][rr0][jc * 8], Ahi + ga0);
    async16(&As[b][1][rr0][jc * 8], Alo + ga0);
    async16(&Bs[b][0][rr0][jc * 8], Bhi + gb0);
    async16(&Bs[b][1][rr0][jc * 8], Blo + gb0);
    async16(&As[b][0][rr1][jc * 8], Ahi + ga1);
    async16(&As[b][1][rr1][jc * 8], Alo + ga1);
    async16(&Bs[b][0][rr1][jc * 8], Bhi + gb1);
    async16(&Bs[b][1][rr1][jc * 8], Blo + gb1);
  };

  const int nt = K >> 5;
  stage(0, 0);
  __syncthreads();  // vmcnt(0): buf0 ready
  int cur = 0;
  for (int t = 0; t < nt; ++t) {
    if (t + 1 < nt) stage(cur ^ 1, (t + 1) << 5);  // async, drains at end barrier

    half8 ah[4], al[4], bh[4], bl[4];
#pragma unroll
    for (int mi = 0; mi < 4; ++mi) {
      int mrow = wm * 64 + mi * 16 + r;
      int js = (quad ^ ((mrow >> 1) & 3)) * 8;
      ah[mi] = *(const half8*)&As[cur][0][mrow][js];
      al[mi] = *(const half8*)&As[cur][1][mrow][js];
    }
#pragma unroll
    for (int ni = 0; ni < 4; ++ni) {
      int nrow = wn * 64 + ni * 16 + r;
      int js = (quad ^ ((nrow >> 1) & 3)) * 8;
      bh[ni] = *(const half8*)&Bs[cur][0][nrow][js];
      bl[ni] = *(const half8*)&Bs[cur][1][nrow][js];
    }
#pragma unroll
    for (int mi = 0; mi < 4; ++mi)
#pragma unroll
      for (int ni = 0; ni < 4; ++ni) {
        acc[mi][ni] = __builtin_amdgcn_mfma_f32_16x16x32_f16(ah[mi], bh[ni], acc[mi][ni], 0, 0, 0);
        acc[mi][ni] = __builtin_amdgcn_mfma_f32_16x16x32_f16(ah[mi], bl[ni], acc[mi][ni], 0, 0, 0);
        acc[mi][ni] = __builtin_amdgcn_mfma_f32_16x16x32_f16(al[mi], bh[ni], acc[mi][ni], 0, 0, 0);
      }
    __syncthreads();  // drains next-buf DMAs + orders LDS reads vs next stage
    cur ^= 1;
  }

  // epilogue: C/D layout col=lane&15, row=quad*4+reg. PLAIN stores: letting L2
  // buffer Y (instead of nt write-through) measured faster overall (R0->R1).
#pragma unroll
  for (int mi = 0; mi < 4; ++mi)
#pragma unroll
    for (int reg = 0; reg < 4; ++reg) {
      int grow = row0 + wm * 64 + mi * 16 + quad * 4 + reg;
      if (grow < M) {
#pragma unroll
        for (int ni = 0; ni < 4; ++ni)
          C[(size_t)grow * HDIM + col0 + wn * 64 + ni * 16 + r] = acc[mi][ni][reg];
      }
    }
}

// ---------------- CSR aggregation (wave-per-node, full 512-feat row) ----------------
// xrelu = relu(b + dinv_i^2*h_i + sum coef*h_src); emit fp16 hi/lo (+ optional fp32)
// Fabric-bound at ~4.3 TB/s beyond-L2 (R0/R1/R3 all measured it). PLAIN 16B
// stores: nt half8 stores measured +11.5 MB WRITE_SIZE per dispatch (R3) --
// nt defeats line-granularity write combining here.

__global__ __launch_bounds__(256) void k_agg(const float* __restrict__ h,
    _Float16* __restrict__ xhi, _Float16* __restrict__ xlo, float* __restrict__ xf,
    const int* __restrict__ row_start, const int* __restrict__ csr_src,
    const float* __restrict__ csr_coef, const float* __restrict__ dinv,
    const float* __restrict__ bias) {
  int wid = threadIdx.x >> 6, lane = threadIdx.x & 63;
  int i = blockIdx.x * 4 + wid;
  if (i >= NN) return;
  int c = lane * 8;  // feats [c, c+8)
  float di = dinv[i];
  float d2 = di * di;
  const f4* hrow = (const f4*)(h + (size_t)i * HDIM + c);
  f4 a0 = hrow[0] * d2, b0 = hrow[1] * d2;
  f4 z = {0.f, 0.f, 0.f, 0.f};
  f4 a1 = z, b1 = z, a2 = z, b2 = z, a3 = z, b3 = z;
  int e0 = row_start[i], e1 = row_start[i + 1];
  int e = e0;
  // 4 independent row-gathers (8 dwordx4 loads) in flight per wave
  for (; e + 4 <= e1; e += 4) {
    int s0 = csr_src[e], s1 = csr_src[e + 1], s2 = csr_src[e + 2], s3 = csr_src[e + 3];
    float c0 = csr_coef[e], c1 = csr_coef[e + 1], c2 = csr_coef[e + 2], c3 = csr_coef[e + 3];
    const f4* r0 = (const f4*)(h + (size_t)s0 * HDIM + c);
    const f4* r1 = (const f4*)(h + (size_t)s1 * HDIM + c);
    const f4* r2 = (const f4*)(h + (size_t)s2 * HDIM + c);
    const f4* r3 = (const f4*)(h + (size_t)s3 * HDIM + c);
    f4 p0 = r0[0], q0 = r0[1];
    f4 p1 = r1[0], q1 = r1[1];
    f4 p2 = r2[0], q2 = r2[1];
    f4 p3 = r3[0], q3 = r3[1];
    a0 += p0 * c0; b0 += q0 * c0;
    a1 += p1 * c1; b1 += q1 * c1;
    a2 += p2 * c2; b2 += q2 * c2;
    a3 += p3 * c3; b3 += q3 * c3;
  }
  for (; e < e1; ++e) {
    int s = csr_src[e];
    float cf = csr_coef[e];
    const f4* r = (const f4*)(h + (size_t)s * HDIM + c);
    a0 += r[0] * cf;
    b0 += r[1] * cf;
  }
  f4 accA = (a0 + a1) + (a2 + a3);
  f4 accB = (b0 + b1) + (b2 + b3);
  accA += *(const f4*)(bias + c);
  accB += *(const f4*)(bias + c + 4);
#pragma unroll
  for (int q = 0; q < 4; ++q) {
    accA[q] = fmaxf(accA[q], 0.f);
    accB[q] = fmaxf(accB[q], 0.f);
  }
  half8 hh, ll;
#pragma unroll
  for (int q = 0; q < 4; ++q) {
    _Float16 hv = (_Float16)accA[q];
    hh[q] = hv;
    ll[q] = (_Float16)(accA[q] - (float)hv);
    _Float16 hv2 = (_Float16)accB[q];
    hh[q + 4] = hv2;
    ll[q + 4] = (_Float16)(accB[q] - (float)hv2);
  }
  *(half8*)(xhi + (size_t)i * HDIM + c) = hh;
  *(half8*)(xlo + (size_t)i * HDIM + c) = ll;
  if (xf) {
    f4* xo = (f4*)(xf + (size_t)i * HDIM + c);
    xo[0] = accA;
    xo[1] = accB;
  }
}

// final conv: h3[N,3] = X[N,512] @ W1[512,3]; one wave per node
__global__ __launch_bounds__(256) void k_gemm3(const float* __restrict__ X, const float* __restrict__ W1,
    float* __restrict__ h3) {
  int wid = threadIdx.x >> 6, lane = threadIdx.x & 63;
  int i = blockIdx.x * 4 + wid;
  if (i >= NN) return;
  const float* xi = X + (size_t)i * HDIM;
  float a0 = 0.f, a1 = 0.f, a2 = 0.f;
#pragma unroll
  for (int t = 0; t < HDIM / 64; ++t) {
    int k = t * 64 + lane;
    float v = xi[k];
    a0 = fmaf(v, W1[k * 3 + 0], a0);
    a1 = fmaf(v, W1[k * 3 + 1], a1);
    a2 = fmaf(v, W1[k * 3 + 2], a2);
  }
#pragma unroll
  for (int off = 32; off > 0; off >>= 1) {
    a0 += __shfl_down(a0, off);
    a1 += __shfl_down(a1, off);
    a2 += __shfl_down(a2, off);
  }
  if (lane == 0) {
    h3[(size_t)i * 3 + 0] = a0;
    h3[(size_t)i * 3 + 1] = a1;
    h3[(size_t)i * 3 + 2] = a2;
  }
}

__global__ __launch_bounds__(256) void k_agg3(const float* __restrict__ h3, float* __restrict__ out,
    const int* __restrict__ row_start, const int* __restrict__ csr_src,
    const float* __restrict__ csr_coef, const float* __restrict__ dinv,
    const float* __restrict__ b1) {
  int i = blockIdx.x * 256 + threadIdx.x;
  if (i >= NN) return;
  float d2 = dinv[i] * dinv[i];
  float o0 = h3[(size_t)i * 3 + 0] * d2;
  float o1 = h3[(size_t)i * 3 + 1] * d2;
  float o2 = h3[(size_t)i * 3 + 2] * d2;
  int e0 = row_start[i], e1 = row_start[i + 1];
  for (int e = e0; e < e1; ++e) {
    int s = csr_src[e];
    float c = csr_coef[e];
    o0 = fmaf(c, h3[(size_t)s * 3 + 0], o0);
    o1 = fmaf(c, h3[(size_t)s * 3 + 1], o1);
    o2 = fmaf(c, h3[(size_t)s * 3 + 2], o2);
  }
  out[(size_t)i * 3 + 0] = o0 + b1[0];
  out[(size_t)i * 3 + 1] = o1 + b1[1];
  out[(size_t)i * 3 + 2] = o2 + b1[2];
}

// ---------------- launch ----------------

extern "C" void kernel_launch(void* const* d_in, const int* in_sizes, int n_in,
                              void* d_out, int out_size, void* d_ws, size_t ws_size,
                              hipStream_t stream) {
  const float* x  = (const float*)d_in[0];
  const int*   ei = (const int*)d_in[1];
  const float* W0 = (const float*)d_in[2];
  const float* b0 = (const float*)d_in[3];
  const float* Wr = (const float*)d_in[4];
  const float* br = (const float*)d_in[5];
  const float* W1 = (const float*)d_in[6];
  const float* b1 = (const float*)d_in[7];
  float* out = (float*)d_out;
  float* X = out + (size_t)NN * CDIM;  // final relu'd state [NN, HDIM] == output 1

  char* ws = (char*)d_ws;
  size_t off = 0;
  auto alloc = [&](size_t bytes) -> void* {
    void* p = ws + off;
    off = (off + bytes + 255) & ~(size_t)255;
    return p;
  };
  float*     Y      = (float*)alloc((size_t)NN * HDIM * 4);        // 102.4 MB
  _Float16*  Xhi    = (_Float16*)alloc((size_t)NN * HDIM * 2);     // 51.2 MB
  _Float16*  Xlo    = (_Float16*)alloc((size_t)NN * HDIM * 2);     // 51.2 MB
  _Float16*  W0thi  = (_Float16*)alloc((size_t)FDIM * HDIM * 2);
  _Float16*  W0tlo  = (_Float16*)alloc((size_t)FDIM * HDIM * 2);
  _Float16*  Wrthi  = (_Float16*)alloc((size_t)NBLK * 2 * HDIM * HDIM * 2);
  _Float16*  Wrtlo  = (_Float16*)alloc((size_t)NBLK * 2 * HDIM * HDIM * 2);
  float*     csr_coef = (float*)alloc((size_t)NE * 4);
  float*     dinv     = (float*)alloc((size_t)NN * 4);
  float*     h3       = (float*)alloc((size_t)NN * CDIM * 4);
  int*       cnt      = (int*)alloc((size_t)NN * 4);
  int*       fill     = (int*)alloc((size_t)NN * 4);
  int*       row_start= (int*)alloc((size_t)(NN + 1) * 4);
  int*       csr_src  = (int*)alloc((size_t)NE * 4);

  const int* src = ei;
  const int* dst = ei + NE;

  // ---- setup (once per call; reused by all 14 layers) ----
  k_zero_i32<<<(NN + 255) / 256, 256, 0, stream>>>(cnt, NN);
  k_zero_i32<<<(NN + 255) / 256, 256, 0, stream>>>(fill, NN);
  k_hist<<<(NE + 255) / 256, 256, 0, stream>>>(dst, cnt);
  k_dinv<<<(NN + 255) / 256, 256, 0, stream>>>(cnt, dinv);
  k_scan<<<1, 1024, 0, stream>>>(cnt, row_start);
  k_fill<<<(NE + 255) / 256, 256, 0, stream>>>(src, dst, row_start, fill, dinv, csr_src, csr_coef);

  // weight + input conversion (hi/lo fp16, weights transposed to [N][K])
  k_cvt_x<<<(NN * FDIM / 4 + 255) / 256, 256, 0, stream>>>(x, Xhi, Xlo, NN * FDIM / 4);
  {
    dim3 g0(FDIM / 32, HDIM / 32, 1);
    k_cvt_wt<<<g0, 256, 0, stream>>>(W0, W0thi, W0tlo, FDIM, HDIM);
    dim3 gr(HDIM / 32, HDIM / 32, NBLK * 2);
    k_cvt_wt<<<gr, 256, 0, stream>>>(Wr, Wrthi, Wrtlo, HDIM, HDIM);
  }

  const int nrb = (NN + 127) / 128;          // 391 row blocks
  const int rpx = (nrb + 7) / 8;             // 49 per XCD
  const int gemm_blocks = 8 * rpx * 4;       // 1568 (XCD-swizzled 1D grid)
  dim3 agg_grid((NN + 3) / 4);               // wave per node, full 512 feats

  // conv0: (x0 hi/lo live in the head of Xhi/Xlo; consumed before agg overwrites)
  k_gemm16<<<gemm_blocks, 256, 0, stream>>>(Xhi, Xlo, W0thi, W0tlo, Y, NN, FDIM);
  k_agg<<<agg_grid, 256, 0, stream>>>(Y, Xhi, Xlo, nullptr, row_start, csr_src, csr_coef, dinv, b0);

  // 6 residual blocks x 2 convs, all H->H
  for (int ib = 0; ib < NBLK; ++ib) {
    for (int j = 0; j < 2; ++j) {
      int li = ib * 2 + j;
      const _Float16* Wh = Wrthi + (size_t)li * HDIM * HDIM;
      const _Float16* Wl = Wrtlo + (size_t)li * HDIM * HDIM;
      const float* bb = br + (size_t)li * HDIM;
      bool last = (ib == NBLK - 1) && (j == 1);
      k_gemm16<<<gemm_blocks, 256, 0, stream>>>(Xhi, Xlo, Wh, Wl, Y, NN, HDIM);
      k_agg<<<agg_grid, 256, 0, stream>>>(Y, Xhi, Xlo, last ? X : nullptr,
                                          row_start, csr_src, csr_coef, dinv, bb);
    }
  }

  // final conv: X (relu'd, fp32) @ W1 -> out[N,3]
  k_gemm3<<<(NN + 3) / 4, 256, 0, stream>>>(X, W1, h3);
  k_agg3<<<(NN + 255) / 256, 256, 0, stream>>>(h3, out, row_start, csr_src, csr_coef, dinv, b1);
}

// Round 5
// 2252.631 us; speedup vs baseline: 1.4689x; 1.3887x over previous
//
#include <hip/hip_runtime.h>
#include <cstdint>
#include <cstddef>

#define NN   50000
#define NE   400000
#define FDIM 256
#define HDIM 512
#define CDIM 3
#define NBLK 6

typedef __attribute__((ext_vector_type(4))) float f4;
typedef __attribute__((ext_vector_type(4))) float f32x4;
typedef _Float16 half8 __attribute__((ext_vector_type(8)));
typedef _Float16 half4 __attribute__((ext_vector_type(4)));

template <typename T>
__device__ inline void nt_store(T* p, T v) { __builtin_nontemporal_store(v, p); }

// async global->LDS 16B copy (global_load_lds_dwordx4). LDS dest must be
// wave-uniform base + lane*16 (HW constraint); our staging index is linear in
// lane so this holds. Global src is per-lane (allowed) -> source-side swizzle.
typedef __attribute__((address_space(1))) const void glob_void;
typedef __attribute__((address_space(3))) void lds_void;
__device__ __forceinline__ void async16(void* lds, const void* g) {
  __builtin_amdgcn_global_load_lds((glob_void*)g, (lds_void*)lds, 16, 0, 0);
}

__device__ __forceinline__ void h8_to_f4(half8 v, f4& lo, f4& hi) {
  lo = (f4){(float)v[0], (float)v[1], (float)v[2], (float)v[3]};
  hi = (f4){(float)v[4], (float)v[5], (float)v[6], (float)v[7]};
}

// ---------------- setup kernels ----------------

__global__ __launch_bounds__(256) void k_zero_i32(int* p, int n) {
  int i = blockIdx.x * 256 + threadIdx.x;
  if (i < n) p[i] = 0;
}

__global__ __launch_bounds__(256) void k_hist(const int* __restrict__ dst, int* __restrict__ cnt) {
  int e = blockIdx.x * 256 + threadIdx.x;
  if (e < NE) {
    int d = dst[e];
    if ((unsigned)d < (unsigned)NN) atomicAdd(&cnt[d], 1);
  }
}

__global__ __launch_bounds__(256) void k_dinv(const int* __restrict__ cnt, float* __restrict__ dinv) {
  int i = blockIdx.x * 256 + threadIdx.x;
  if (i < NN) dinv[i] = rsqrtf((float)cnt[i] + 1.0f);
}

// single-block exclusive scan of cnt[NN] -> row_start[NN+1]
__global__ __launch_bounds__(1024) void k_scan(const int* __restrict__ cnt, int* __restrict__ row_start) {
  __shared__ int wsum[16];
  __shared__ int carry_s;
  int tid = threadIdx.x, lane = tid & 63, wid = tid >> 6;
  if (tid == 0) carry_s = 0;
  __syncthreads();
  for (int base = 0; base < NN; base += 1024) {
    int i = base + tid;
    int v = (i < NN) ? cnt[i] : 0;
    int incl = v;
#pragma unroll
    for (int off = 1; off < 64; off <<= 1) {
      int t = __shfl_up(incl, off);
      if (lane >= off) incl += t;
    }
    if (lane == 63) wsum[wid] = incl;
    __syncthreads();
    int woff = 0;
    for (int w = 0; w < wid; ++w) woff += wsum[w];
    int excl = carry_s + woff + (incl - v);
    if (i < NN) row_start[i] = excl;
    __syncthreads();
    if (tid == 1023) carry_s = excl + v;
    __syncthreads();
  }
  if (threadIdx.x == 0) row_start[NN] = carry_s;
}

__global__ __launch_bounds__(256) void k_fill(const int* __restrict__ src, const int* __restrict__ dst,
    const int* __restrict__ row_start, int* __restrict__ fill,
    const float* __restrict__ dinv, int* __restrict__ csr_src, float* __restrict__ csr_coef) {
  int e = blockIdx.x * 256 + threadIdx.x;
  if (e >= NE) return;
  int s = src[e], d = dst[e];
  if ((unsigned)s >= (unsigned)NN || (unsigned)d >= (unsigned)NN) return;
  int pos = row_start[d] + atomicAdd(&fill[d], 1);
  csr_src[pos] = s;
  csr_coef[pos] = dinv[s] * dinv[d];
}

// ---------------- conversion kernels ----------------

// x [N,256] fp32 -> hi/lo fp16 (no relu, no transpose)
__global__ __launch_bounds__(256) void k_cvt_x(const float* __restrict__ x,
    _Float16* __restrict__ xhi, _Float16* __restrict__ xlo, int n4) {
  int i = blockIdx.x * 256 + threadIdx.x;
  if (i >= n4) return;
  f4 v = ((const f4*)x)[i];
  half4 h, l;
#pragma unroll
  for (int c = 0; c < 4; ++c) {
    float vv = v[c];
    _Float16 hh = (_Float16)vv;
    h[c] = hh;
    l[c] = (_Float16)(vv - (float)hh);
  }
  ((half4*)xhi)[i] = h;
  ((half4*)xlo)[i] = l;
}

// W [K,N] fp32 -> transposed hi/lo fp16 [N,K]  (z = matrix index)
__global__ __launch_bounds__(256) void k_cvt_wt(const float* __restrict__ W,
    _Float16* __restrict__ Whi, _Float16* __restrict__ Wlo, int K, int N) {
  __shared__ float tile[32][33];
  int l = blockIdx.z;
  const float* Wl = W + (size_t)l * K * N;
  _Float16* Oh = Whi + (size_t)l * K * N;
  _Float16* Ol = Wlo + (size_t)l * K * N;
  int k0 = blockIdx.x * 32, n0 = blockIdx.y * 32;
  int tx = threadIdx.x & 31, ty = threadIdx.x >> 5;
#pragma unroll
  for (int p = 0; p < 4; ++p)
    tile[ty + 8 * p][tx] = Wl[(size_t)(k0 + ty + 8 * p) * N + n0 + tx];
  __syncthreads();
#pragma unroll
  for (int p = 0; p < 4; ++p) {
    int n = n0 + ty + 8 * p, k = k0 + tx;
    float v = tile[tx][ty + 8 * p];
    _Float16 hi = (_Float16)v;
    Oh[(size_t)n * K + k] = hi;
    Ol[(size_t)n * K + k] = (_Float16)(v - (float)hi);
  }
}

// ---------------- MFMA GEMM: Yh[M,512](fp16) = (Ahi+Alo)[M,K] @ (Bhi+Blo)^T ----
// A: [M,K] fp16 hi/lo; B: [N,K] fp16 hi/lo (pre-transposed, k-contiguous)
// fp32 accum via 3-term split: ah*bh + ah*bl + al*bh. OUTPUT IS fp16: every
// consumer term in the aggregation carries coef ~ 1/deg (~0.11), so fp16
// rounding of Y adds only ~0.3*2^-11*|h| per layer -- while halving the agg's
// gather bytes AND Y writeback AND the GEMM's store traffic.
// Staging: global_load_lds width=16, 2-phase double buffer (R4 structure):
//   iter t: STAGE(buf^1, t+1) ; ds_read buf ; MFMA ; barrier (drains vmcnt)
// Bank conflicts on b128 fragment reads avoided by chunk XOR swizzle applied
// on the GLOBAL SOURCE address: LDS slot (row,j) holds chunk (row, j^((row>>1)&3));
// fragment read uses the same XOR. DMA dest stays lane-linear (HW constraint).
// A-tile rows >= M stage row M-1 (clamped; dead data, out rows >=M not stored).

__global__ __launch_bounds__(256) void k_gemm16(
    const _Float16* __restrict__ Ahi, const _Float16* __restrict__ Alo,
    const _Float16* __restrict__ Bhi, const _Float16* __restrict__ Blo,
    _Float16* __restrict__ C, int M, int K) {
  const int nrb = (M + 127) >> 7;         // row blocks (391)
  const int rpx = (nrb + 7) >> 3;         // row blocks per XCD (49)
  const int f = blockIdx.x;
  const int q8 = f & 7, s = f >> 3;
  const int rb = q8 * rpx + (s >> 2);
  const int cb = s & 3;
  if (rb >= nrb) return;
  const int row0 = rb * 128, col0 = cb * 128;

  __shared__ _Float16 As[2][2][128][32];   // [buf][hi/lo][row][k]
  __shared__ _Float16 Bs[2][2][128][32];
  const int tid = threadIdx.x;
  const int lane = tid & 63, wave = tid >> 6;
  const int wm = wave & 1, wn = wave >> 1;
  const int quad = lane >> 4, r = lane & 15;

  // staging: thread handles rows rr0 and rr0+64, chunk jc (16B each)
  const int rr0 = tid >> 2, jc = tid & 3;
  const int rr1 = rr0 + 64;
  const int gj0 = jc ^ ((rr0 >> 1) & 3);
  const int gj1 = jc ^ ((rr1 >> 1) & 3);
  const int ar0 = min(row0 + rr0, M - 1);   // clamp A rows (in-bounds)
  const int ar1 = min(row0 + rr1, M - 1);
  const int br0 = col0 + rr0, br1 = col0 + rr1;

  f32x4 acc[4][4];
#pragma unroll
  for (int i = 0; i < 4; ++i)
#pragma unroll
    for (int j = 0; j < 4; ++j) acc[i][j] = (f32x4){0.f, 0.f, 0.f, 0.f};

  auto stage = [&](int b, int k0) {
    size_t ga0 = (size_t)ar0 * K + k0 + gj0 * 8;
    size_t gb0 = (size_t)br0 * K + k0 + gj0 * 8;
    size_t ga1 = (size_t)ar1 * K + k0 + gj1 * 8;
    size_t gb1 = (size_t)br1 * K + k0 + gj1 * 8;
    async16(&As[b][0][rr0][jc * 8], Ahi + ga0);
    async16(&As[b][1][rr0][jc * 8], Alo + ga0);
    async16(&Bs[b][0][rr0][jc * 8], Bhi + gb0);
    async16(&Bs[b][1][rr0][jc * 8], Blo + gb0);
    async16(&As[b][0][rr1][jc * 8], Ahi + ga1);
    async16(&As[b][1][rr1][jc * 8], Alo + ga1);
    async16(&Bs[b][0][rr1][jc * 8], Bhi + gb1);
    async16(&Bs[b][1][rr1][jc * 8], Blo + gb1);
  };

  const int nt = K >> 5;
  stage(0, 0);
  __syncthreads();  // vmcnt(0): buf0 ready
  int cur = 0;
  for (int t = 0; t < nt; ++t) {
    if (t + 1 < nt) stage(cur ^ 1, (t + 1) << 5);  // async, drains at end barrier

    half8 ah[4], al[4], bh[4], bl[4];
#pragma unroll
    for (int mi = 0; mi < 4; ++mi) {
      int mrow = wm * 64 + mi * 16 + r;
      int js = (quad ^ ((mrow >> 1) & 3)) * 8;
      ah[mi] = *(const half8*)&As[cur][0][mrow][js];
      al[mi] = *(const half8*)&As[cur][1][mrow][js];
    }
#pragma unroll
    for (int ni = 0; ni < 4; ++ni) {
      int nrow = wn * 64 + ni * 16 + r;
      int js = (quad ^ ((nrow >> 1) & 3)) * 8;
      bh[ni] = *(const half8*)&Bs[cur][0][nrow][js];
      bl[ni] = *(const half8*)&Bs[cur][1][nrow][js];
    }
#pragma unroll
    for (int mi = 0; mi < 4; ++mi)
#pragma unroll
      for (int ni = 0; ni < 4; ++ni) {
        acc[mi][ni] = __builtin_amdgcn_mfma_f32_16x16x32_f16(ah[mi], bh[ni], acc[mi][ni], 0, 0, 0);
        acc[mi][ni] = __builtin_amdgcn_mfma_f32_16x16x32_f16(ah[mi], bl[ni], acc[mi][ni], 0, 0, 0);
        acc[mi][ni] = __builtin_amdgcn_mfma_f32_16x16x32_f16(al[mi], bh[ni], acc[mi][ni], 0, 0, 0);
      }
    __syncthreads();  // drains next-buf DMAs + orders LDS reads vs next stage
    cur ^= 1;
  }

  // epilogue: C/D layout col=lane&15, row=quad*4+reg; emit fp16. Per (row,wave)
  // the 16 lanes x 4 ni cover 64 consecutive halves (128B) -> L2 line-merges.
#pragma unroll
  for (int mi = 0; mi < 4; ++mi)
#pragma unroll
    for (int reg = 0; reg < 4; ++reg) {
      int grow = row0 + wm * 64 + mi * 16 + quad * 4 + reg;
      if (grow < M) {
#pragma unroll
        for (int ni = 0; ni < 4; ++ni)
          C[(size_t)grow * HDIM + col0 + wn * 64 + ni * 16 + r] = (_Float16)acc[mi][ni][reg];
      }
    }
}

// ---------------- CSR aggregation (wave-per-node, full 512-feat row) ----------------
// xrelu = relu(b + dinv_i^2*h_i + sum coef*h_src); h is fp16 -> ONE 16B load
// per neighbor row per lane (was two). 8-deep edge unroll keeps 8 gathers in
// flight. Emit X as fp16 hi/lo (+ optional fp32). Plain 16B stores (R3: nt
// half8 cost +11.5MB WRITE).

__global__ __launch_bounds__(256) void k_agg(const _Float16* __restrict__ h,
    _Float16* __restrict__ xhi, _Float16* __restrict__ xlo, float* __restrict__ xf,
    const int* __restrict__ row_start, const int* __restrict__ csr_src,
    const float* __restrict__ csr_coef, const float* __restrict__ dinv,
    const float* __restrict__ bias) {
  int wid = threadIdx.x >> 6, lane = threadIdx.x & 63;
  int i = blockIdx.x * 4 + wid;
  if (i >= NN) return;
  int c = lane * 8;  // feats [c, c+8)
  float di = dinv[i];
  float d2 = di * di;
  half8 hv = *(const half8*)(h + (size_t)i * HDIM + c);
  f4 sA, sB;
  h8_to_f4(hv, sA, sB);
  f4 a0 = sA * d2, b0 = sB * d2;
  f4 z = {0.f, 0.f, 0.f, 0.f};
  f4 a1 = z, b1 = z, a2 = z, b2 = z, a3 = z, b3 = z;
  int e0 = row_start[i], e1 = row_start[i + 1];
  int e = e0;
  // 8 independent row-gathers (8 dwordx4 loads) in flight per wave
  for (; e + 8 <= e1; e += 8) {
    int s0 = csr_src[e], s1 = csr_src[e + 1], s2 = csr_src[e + 2], s3 = csr_src[e + 3];
    int s4 = csr_src[e + 4], s5 = csr_src[e + 5], s6 = csr_src[e + 6], s7 = csr_src[e + 7];
    float c0 = csr_coef[e], c1 = csr_coef[e + 1], c2 = csr_coef[e + 2], c3 = csr_coef[e + 3];
    float c4 = csr_coef[e + 4], c5 = csr_coef[e + 5], c6 = csr_coef[e + 6], c7 = csr_coef[e + 7];
    half8 r0 = *(const half8*)(h + (size_t)s0 * HDIM + c);
    half8 r1 = *(const half8*)(h + (size_t)s1 * HDIM + c);
    half8 r2 = *(const half8*)(h + (size_t)s2 * HDIM + c);
    half8 r3 = *(const half8*)(h + (size_t)s3 * HDIM + c);
    half8 r4 = *(const half8*)(h + (size_t)s4 * HDIM + c);
    half8 r5 = *(const half8*)(h + (size_t)s5 * HDIM + c);
    half8 r6 = *(const half8*)(h + (size_t)s6 * HDIM + c);
    half8 r7 = *(const half8*)(h + (size_t)s7 * HDIM + c);
    f4 pA, pB;
    h8_to_f4(r0, pA, pB); a0 += pA * c0; b0 += pB * c0;
    h8_to_f4(r1, pA, pB); a1 += pA * c1; b1 += pB * c1;
    h8_to_f4(r2, pA, pB); a2 += pA * c2; b2 += pB * c2;
    h8_to_f4(r3, pA, pB); a3 += pA * c3; b3 += pB * c3;
    h8_to_f4(r4, pA, pB); a0 += pA * c4; b0 += pB * c4;
    h8_to_f4(r5, pA, pB); a1 += pA * c5; b1 += pB * c5;
    h8_to_f4(r6, pA, pB); a2 += pA * c6; b2 += pB * c6;
    h8_to_f4(r7, pA, pB); a3 += pA * c7; b3 += pB * c7;
  }
  for (; e + 4 <= e1; e += 4) {
    int s0 = csr_src[e], s1 = csr_src[e + 1], s2 = csr_src[e + 2], s3 = csr_src[e + 3];
    float c0 = csr_coef[e], c1 = csr_coef[e + 1], c2 = csr_coef[e + 2], c3 = csr_coef[e + 3];
    half8 r0 = *(const half8*)(h + (size_t)s0 * HDIM + c);
    half8 r1 = *(const half8*)(h + (size_t)s1 * HDIM + c);
    half8 r2 = *(const half8*)(h + (size_t)s2 * HDIM + c);
    half8 r3 = *(const half8*)(h + (size_t)s3 * HDIM + c);
    f4 pA, pB;
    h8_to_f4(r0, pA, pB); a0 += pA * c0; b0 += pB * c0;
    h8_to_f4(r1, pA, pB); a1 += pA * c1; b1 += pB * c1;
    h8_to_f4(r2, pA, pB); a2 += pA * c2; b2 += pB * c2;
    h8_to_f4(r3, pA, pB); a3 += pA * c3; b3 += pB * c3;
  }
  for (; e < e1; ++e) {
    int s = csr_src[e];
    float cf = csr_coef[e];
    half8 r0 = *(const half8*)(h + (size_t)s * HDIM + c);
    f4 pA, pB;
    h8_to_f4(r0, pA, pB);
    a0 += pA * cf; b0 += pB * cf;
  }
  f4 accA = (a0 + a1) + (a2 + a3);
  f4 accB = (b0 + b1) + (b2 + b3);
  accA += *(const f4*)(bias + c);
  accB += *(const f4*)(bias + c + 4);
#pragma unroll
  for (int q = 0; q < 4; ++q) {
    accA[q] = fmaxf(accA[q], 0.f);
    accB[q] = fmaxf(accB[q], 0.f);
  }
  half8 hh, ll;
#pragma unroll
  for (int q = 0; q < 4; ++q) {
    _Float16 hvv = (_Float16)accA[q];
    hh[q] = hvv;
    ll[q] = (_Float16)(accA[q] - (float)hvv);
    _Float16 hv2 = (_Float16)accB[q];
    hh[q + 4] = hv2;
    ll[q + 4] = (_Float16)(accB[q] - (float)hv2);
  }
  *(half8*)(xhi + (size_t)i * HDIM + c) = hh;
  *(half8*)(xlo + (size_t)i * HDIM + c) = ll;
  if (xf) {
    f4* xo = (f4*)(xf + (size_t)i * HDIM + c);
    xo[0] = accA;
    xo[1] = accB;
  }
}

// final conv: h3[N,3] = X[N,512] @ W1[512,3]; one wave per node
__global__ __launch_bounds__(256) void k_gemm3(const float* __restrict__ X, const float* __restrict__ W1,
    float* __restrict__ h3) {
  int wid = threadIdx.x >> 6, lane = threadIdx.x & 63;
  int i = blockIdx.x * 4 + wid;
  if (i >= NN) return;
  const float* xi = X + (size_t)i * HDIM;
  float a0 = 0.f, a1 = 0.f, a2 = 0.f;
#pragma unroll
  for (int t = 0; t < HDIM / 64; ++t) {
    int k = t * 64 + lane;
    float v = xi[k];
    a0 = fmaf(v, W1[k * 3 + 0], a0);
    a1 = fmaf(v, W1[k * 3 + 1], a1);
    a2 = fmaf(v, W1[k * 3 + 2], a2);
  }
#pragma unroll
  for (int off = 32; off > 0; off >>= 1) {
    a0 += __shfl_down(a0, off);
    a1 += __shfl_down(a1, off);
    a2 += __shfl_down(a2, off);
  }
  if (lane == 0) {
    h3[(size_t)i * 3 + 0] = a0;
    h3[(size_t)i * 3 + 1] = a1;
    h3[(size_t)i * 3 + 2] = a2;
  }
}

__global__ __launch_bounds__(256) void k_agg3(const float* __restrict__ h3, float* __restrict__ out,
    const int* __restrict__ row_start, const int* __restrict__ csr_src,
    const float* __restrict__ csr_coef, const float* __restrict__ dinv,
    const float* __restrict__ b1) {
  int i = blockIdx.x * 256 + threadIdx.x;
  if (i >= NN) return;
  float d2 = dinv[i] * dinv[i];
  float o0 = h3[(size_t)i * 3 + 0] * d2;
  float o1 = h3[(size_t)i * 3 + 1] * d2;
  float o2 = h3[(size_t)i * 3 + 2] * d2;
  int e0 = row_start[i], e1 = row_start[i + 1];
  for (int e = e0; e < e1; ++e) {
    int s = csr_src[e];
    float c = csr_coef[e];
    o0 = fmaf(c, h3[(size_t)s * 3 + 0], o0);
    o1 = fmaf(c, h3[(size_t)s * 3 + 1], o1);
    o2 = fmaf(c, h3[(size_t)s * 3 + 2], o2);
  }
  out[(size_t)i * 3 + 0] = o0 + b1[0];
  out[(size_t)i * 3 + 1] = o1 + b1[1];
  out[(size_t)i * 3 + 2] = o2 + b1[2];
}

// ---------------- launch ----------------

extern "C" void kernel_launch(void* const* d_in, const int* in_sizes, int n_in,
                              void* d_out, int out_size, void* d_ws, size_t ws_size,
                              hipStream_t stream) {
  const float* x  = (const float*)d_in[0];
  const int*   ei = (const int*)d_in[1];
  const float* W0 = (const float*)d_in[2];
  const float* b0 = (const float*)d_in[3];
  const float* Wr = (const float*)d_in[4];
  const float* br = (const float*)d_in[5];
  const float* W1 = (const float*)d_in[6];
  const float* b1 = (const float*)d_in[7];
  float* out = (float*)d_out;
  float* X = out + (size_t)NN * CDIM;  // final relu'd state [NN, HDIM] == output 1

  char* ws = (char*)d_ws;
  size_t off = 0;
  auto alloc = [&](size_t bytes) -> void* {
    void* p = ws + off;
    off = (off + bytes + 255) & ~(size_t)255;
    return p;
  };
  _Float16*  Yh     = (_Float16*)alloc((size_t)NN * HDIM * 2);     // 51.2 MB (fp16 Y)
  _Float16*  Xhi    = (_Float16*)alloc((size_t)NN * HDIM * 2);     // 51.2 MB
  _Float16*  Xlo    = (_Float16*)alloc((size_t)NN * HDIM * 2);     // 51.2 MB
  _Float16*  W0thi  = (_Float16*)alloc((size_t)FDIM * HDIM * 2);
  _Float16*  W0tlo  = (_Float16*)alloc((size_t)FDIM * HDIM * 2);
  _Float16*  Wrthi  = (_Float16*)alloc((size_t)NBLK * 2 * HDIM * HDIM * 2);
  _Float16*  Wrtlo  = (_Float16*)alloc((size_t)NBLK * 2 * HDIM * HDIM * 2);
  float*     csr_coef = (float*)alloc((size_t)NE * 4);
  float*     dinv     = (float*)alloc((size_t)NN * 4);
  float*     h3       = (float*)alloc((size_t)NN * CDIM * 4);
  int*       cnt      = (int*)alloc((size_t)NN * 4);
  int*       fill     = (int*)alloc((size_t)NN * 4);
  int*       row_start= (int*)alloc((size_t)(NN + 1) * 4);
  int*       csr_src  = (int*)alloc((size_t)NE * 4);

  const int* src = ei;
  const int* dst = ei + NE;

  // ---- setup (once per call; reused by all 14 layers) ----
  k_zero_i32<<<(NN + 255) / 256, 256, 0, stream>>>(cnt, NN);
  k_zero_i32<<<(NN + 255) / 256, 256, 0, stream>>>(fill, NN);
  k_hist<<<(NE + 255) / 256, 256, 0, stream>>>(dst, cnt);
  k_dinv<<<(NN + 255) / 256, 256, 0, stream>>>(cnt, dinv);
  k_scan<<<1, 1024, 0, stream>>>(cnt, row_start);
  k_fill<<<(NE + 255) / 256, 256, 0, stream>>>(src, dst, row_start, fill, dinv, csr_src, csr_coef);

  // weight + input conversion (hi/lo fp16, weights transposed to [N][K])
  k_cvt_x<<<(NN * FDIM / 4 + 255) / 256, 256, 0, stream>>>(x, Xhi, Xlo, NN * FDIM / 4);
  {
    dim3 g0(FDIM / 32, HDIM / 32, 1);
    k_cvt_wt<<<g0, 256, 0, stream>>>(W0, W0thi, W0tlo, FDIM, HDIM);
    dim3 gr(HDIM / 32, HDIM / 32, NBLK * 2);
    k_cvt_wt<<<gr, 256, 0, stream>>>(Wr, Wrthi, Wrtlo, HDIM, HDIM);
  }

  const int nrb = (NN + 127) / 128;          // 391 row blocks
  const int rpx = (nrb + 7) / 8;             // 49 per XCD
  const int gemm_blocks = 8 * rpx * 4;       // 1568 (XCD-swizzled 1D grid)
  dim3 agg_grid((NN + 3) / 4);               // wave per node, full 512 feats

  // conv0: (x0 hi/lo live in the head of Xhi/Xlo; consumed before agg overwrites)
  k_gemm16<<<gemm_blocks, 256, 0, stream>>>(Xhi, Xlo, W0thi, W0tlo, Yh, NN, FDIM);
  k_agg<<<agg_grid, 256, 0, stream>>>(Yh, Xhi, Xlo, nullptr, row_start, csr_src, csr_coef, dinv, b0);

  // 6 residual blocks x 2 convs, all H->H
  for (int ib = 0; ib < NBLK; ++ib) {
    for (int j = 0; j < 2; ++j) {
      int li = ib * 2 + j;
      const _Float16* Wh = Wrthi + (size_t)li * HDIM * HDIM;
      const _Float16* Wl = Wrtlo + (size_t)li * HDIM * HDIM;
      const float* bb = br + (size_t)li * HDIM;
      bool last = (ib == NBLK - 1) && (j == 1);
      k_gemm16<<<gemm_blocks, 256, 0, stream>>>(Xhi, Xlo, Wh, Wl, Yh, NN, HDIM);
      k_agg<<<agg_grid, 256, 0, stream>>>(Yh, Xhi, Xlo, last ? X : nullptr,
                                          row_start, csr_src, csr_coef, dinv, bb);
    }
  }

  // final conv: X (relu'd, fp32) @ W1 -> out[N,3]
  k_gemm3<<<(NN + 3) / 4, 256, 0, stream>>>(X, W1, h3);
  k_agg3<<<(NN + 255) / 256, 256, 0, stream>>>(h3, out, row_start, csr_src, csr_coef, dinv, b1);
}

// Round 6
// 1880.893 us; speedup vs baseline: 1.7592x; 1.1976x over previous
//
#include <hip/hip_runtime.h>
#include <cstdint>
#include <cstddef>

#define NN   50000
#define NE   400000
#define FDIM 256
#define HDIM 512
#define CDIM 3
#define NBLK 6

typedef __attribute__((ext_vector_type(4))) float f4;
typedef __attribute__((ext_vector_type(4))) float f32x4;
typedef _Float16 half8 __attribute__((ext_vector_type(8)));
typedef _Float16 half4 __attribute__((ext_vector_type(4)));

template <typename T>
__device__ inline void nt_store(T* p, T v) { __builtin_nontemporal_store(v, p); }

// async global->LDS 16B copy (global_load_lds_dwordx4). LDS dest must be
// wave-uniform base + lane*16 (HW constraint); our staging index is linear in
// lane so this holds. Global src is per-lane (allowed) -> source-side swizzle.
typedef __attribute__((address_space(1))) const void glob_void;
typedef __attribute__((address_space(3))) void lds_void;
__device__ __forceinline__ void async16(void* lds, const void* g) {
  __builtin_amdgcn_global_load_lds((glob_void*)g, (lds_void*)lds, 16, 0, 0);
}

__device__ __forceinline__ void h8_to_f4(half8 v, f4& lo, f4& hi) {
  lo = (f4){(float)v[0], (float)v[1], (float)v[2], (float)v[3]};
  hi = (f4){(float)v[4], (float)v[5], (float)v[6], (float)v[7]};
}

// ---------------- setup kernels ----------------

__global__ __launch_bounds__(256) void k_zero_i32(int* p, int n) {
  int i = blockIdx.x * 256 + threadIdx.x;
  if (i < n) p[i] = 0;
}

__global__ __launch_bounds__(256) void k_hist(const int* __restrict__ dst, int* __restrict__ cnt) {
  int e = blockIdx.x * 256 + threadIdx.x;
  if (e < NE) {
    int d = dst[e];
    if ((unsigned)d < (unsigned)NN) atomicAdd(&cnt[d], 1);
  }
}

__global__ __launch_bounds__(256) void k_dinv(const int* __restrict__ cnt, float* __restrict__ dinv) {
  int i = blockIdx.x * 256 + threadIdx.x;
  if (i < NN) dinv[i] = rsqrtf((float)cnt[i] + 1.0f);
}

// single-block exclusive scan of cnt[NN] -> row_start[NN+1]
__global__ __launch_bounds__(1024) void k_scan(const int* __restrict__ cnt, int* __restrict__ row_start) {
  __shared__ int wsum[16];
  __shared__ int carry_s;
  int tid = threadIdx.x, lane = tid & 63, wid = tid >> 6;
  if (tid == 0) carry_s = 0;
  __syncthreads();
  for (int base = 0; base < NN; base += 1024) {
    int i = base + tid;
    int v = (i < NN) ? cnt[i] : 0;
    int incl = v;
#pragma unroll
    for (int off = 1; off < 64; off <<= 1) {
      int t = __shfl_up(incl, off);
      if (lane >= off) incl += t;
    }
    if (lane == 63) wsum[wid] = incl;
    __syncthreads();
    int woff = 0;
    for (int w = 0; w < wid; ++w) woff += wsum[w];
    int excl = carry_s + woff + (incl - v);
    if (i < NN) row_start[i] = excl;
    __syncthreads();
    if (tid == 1023) carry_s = excl + v;
    __syncthreads();
  }
  if (threadIdx.x == 0) row_start[NN] = carry_s;
}

__global__ __launch_bounds__(256) void k_fill(const int* __restrict__ src, const int* __restrict__ dst,
    const int* __restrict__ row_start, int* __restrict__ fill,
    const float* __restrict__ dinv, int* __restrict__ csr_src, float* __restrict__ csr_coef) {
  int e = blockIdx.x * 256 + threadIdx.x;
  if (e >= NE) return;
  int s = src[e], d = dst[e];
  if ((unsigned)s >= (unsigned)NN || (unsigned)d >= (unsigned)NN) return;
  int pos = row_start[d] + atomicAdd(&fill[d], 1);
  csr_src[pos] = s;
  csr_coef[pos] = dinv[s] * dinv[d];
}

// ---------------- conversion kernels ----------------

// x [N,256] fp32 -> fp16 (A-side only needs hi: 2-term GEMM split)
__global__ __launch_bounds__(256) void k_cvt_x(const float* __restrict__ x,
    _Float16* __restrict__ xhi, int n4) {
  int i = blockIdx.x * 256 + threadIdx.x;
  if (i >= n4) return;
  f4 v = ((const f4*)x)[i];
  half4 h;
#pragma unroll
  for (int c = 0; c < 4; ++c) h[c] = (_Float16)v[c];
  ((half4*)xhi)[i] = h;
}

// W [K,N] fp32 -> transposed hi/lo fp16 [N,K]  (z = matrix index)
__global__ __launch_bounds__(256) void k_cvt_wt(const float* __restrict__ W,
    _Float16* __restrict__ Whi, _Float16* __restrict__ Wlo, int K, int N) {
  __shared__ float tile[32][33];
  int l = blockIdx.z;
  const float* Wl = W + (size_t)l * K * N;
  _Float16* Oh = Whi + (size_t)l * K * N;
  _Float16* Ol = Wlo + (size_t)l * K * N;
  int k0 = blockIdx.x * 32, n0 = blockIdx.y * 32;
  int tx = threadIdx.x & 31, ty = threadIdx.x >> 5;
#pragma unroll
  for (int p = 0; p < 4; ++p)
    tile[ty + 8 * p][tx] = Wl[(size_t)(k0 + ty + 8 * p) * N + n0 + tx];
  __syncthreads();
#pragma unroll
  for (int p = 0; p < 4; ++p) {
    int n = n0 + ty + 8 * p, k = k0 + tx;
    float v = tile[tx][ty + 8 * p];
    _Float16 hi = (_Float16)v;
    Oh[(size_t)n * K + k] = hi;
    Ol[(size_t)n * K + k] = (_Float16)(v - (float)hi);
  }
}

// ---------------- MFMA GEMM: Yh[M,512](fp16) = Ah[M,K] @ (Bhi+Blo)^T ----------
// 2-TERM SPLIT: A fp16 single-stream (X quantized); B (weights) hi/lo fp16.
// acc = ah*bh + ah*bl (fp32 accum). The dropped al*bh term is ~2^-11|x||w|*
// sqrt(K) ~ 4e-4 -- same order as the Y-fp16 rounding already present. This
// removes the Alo stream: GEMM A-fetch halves AND agg no longer writes Xlo.
// Staging: global_load_lds width=16, 2-phase double buffer (R4 structure):
//   iter t: STAGE(buf^1, t+1) ; ds_read buf ; MFMA ; barrier (drains vmcnt)
// Bank conflicts on b128 fragment reads avoided by chunk XOR swizzle applied
// on the GLOBAL SOURCE address: LDS slot (row,j) holds chunk (row, j^((row>>1)&3));
// fragment read uses the same XOR. DMA dest stays lane-linear (HW constraint).
// A-tile rows >= M stage row M-1 (clamped; dead data, out rows >=M not stored).
// LDS: As 16KB + Bs 32KB = 48KB (was 64) -> up to 3 blocks/CU.

__global__ __launch_bounds__(256) void k_gemm16(
    const _Float16* __restrict__ Ahi,
    const _Float16* __restrict__ Bhi, const _Float16* __restrict__ Blo,
    _Float16* __restrict__ C, int M, int K) {
  const int nrb = (M + 127) >> 7;         // row blocks (391)
  const int rpx = (nrb + 7) >> 3;         // row blocks per XCD (49)
  const int f = blockIdx.x;
  const int q8 = f & 7, s = f >> 3;
  const int rb = q8 * rpx + (s >> 2);
  const int cb = s & 3;
  if (rb >= nrb) return;
  const int row0 = rb * 128, col0 = cb * 128;

  __shared__ _Float16 As[2][128][32];      // [buf][row][k]
  __shared__ _Float16 Bs[2][2][128][32];   // [buf][hi/lo][row][k]
  const int tid = threadIdx.x;
  const int lane = tid & 63, wave = tid >> 6;
  const int wm = wave & 1, wn = wave >> 1;
  const int quad = lane >> 4, r = lane & 15;

  // staging: thread handles rows rr0 and rr0+64, chunk jc (16B each)
  const int rr0 = tid >> 2, jc = tid & 3;
  const int rr1 = rr0 + 64;
  const int gj0 = jc ^ ((rr0 >> 1) & 3);
  const int gj1 = jc ^ ((rr1 >> 1) & 3);
  const int ar0 = min(row0 + rr0, M - 1);   // clamp A rows (in-bounds)
  const int ar1 = min(row0 + rr1, M - 1);
  const int br0 = col0 + rr0, br1 = col0 + rr1;

  f32x4 acc[4][4];
#pragma unroll
  for (int i = 0; i < 4; ++i)
#pragma unroll
    for (int j = 0; j < 4; ++j) acc[i][j] = (f32x4){0.f, 0.f, 0.f, 0.f};

  auto stage = [&](int b, int k0) {
    size_t ga0 = (size_t)ar0 * K + k0 + gj0 * 8;
    size_t gb0 = (size_t)br0 * K + k0 + gj0 * 8;
    size_t ga1 = (size_t)ar1 * K + k0 + gj1 * 8;
    size_t gb1 = (size_t)br1 * K + k0 + gj1 * 8;
    async16(&As[b][rr0][jc * 8], Ahi + ga0);
    async16(&As[b][rr1][jc * 8], Ahi + ga1);
    async16(&Bs[b][0][rr0][jc * 8], Bhi + gb0);
    async16(&Bs[b][1][rr0][jc * 8], Blo + gb0);
    async16(&Bs[b][0][rr1][jc * 8], Bhi + gb1);
    async16(&Bs[b][1][rr1][jc * 8], Blo + gb1);
  };

  const int nt = K >> 5;
  stage(0, 0);
  __syncthreads();  // vmcnt(0): buf0 ready
  int cur = 0;
  for (int t = 0; t < nt; ++t) {
    if (t + 1 < nt) stage(cur ^ 1, (t + 1) << 5);  // async, drains at end barrier

    half8 ah[4], bh[4], bl[4];
#pragma unroll
    for (int mi = 0; mi < 4; ++mi) {
      int mrow = wm * 64 + mi * 16 + r;
      int js = (quad ^ ((mrow >> 1) & 3)) * 8;
      ah[mi] = *(const half8*)&As[cur][mrow][js];
    }
#pragma unroll
    for (int ni = 0; ni < 4; ++ni) {
      int nrow = wn * 64 + ni * 16 + r;
      int js = (quad ^ ((nrow >> 1) & 3)) * 8;
      bh[ni] = *(const half8*)&Bs[cur][0][nrow][js];
      bl[ni] = *(const half8*)&Bs[cur][1][nrow][js];
    }
#pragma unroll
    for (int mi = 0; mi < 4; ++mi)
#pragma unroll
      for (int ni = 0; ni < 4; ++ni) {
        acc[mi][ni] = __builtin_amdgcn_mfma_f32_16x16x32_f16(ah[mi], bh[ni], acc[mi][ni], 0, 0, 0);
        acc[mi][ni] = __builtin_amdgcn_mfma_f32_16x16x32_f16(ah[mi], bl[ni], acc[mi][ni], 0, 0, 0);
      }
    __syncthreads();  // drains next-buf DMAs + orders LDS reads vs next stage
    cur ^= 1;
  }

  // epilogue: C/D layout col=lane&15, row=quad*4+reg; emit fp16.
#pragma unroll
  for (int mi = 0; mi < 4; ++mi)
#pragma unroll
    for (int reg = 0; reg < 4; ++reg) {
      int grow = row0 + wm * 64 + mi * 16 + quad * 4 + reg;
      if (grow < M) {
#pragma unroll
        for (int ni = 0; ni < 4; ++ni)
          C[(size_t)grow * HDIM + col0 + wn * 64 + ni * 16 + r] = (_Float16)acc[mi][ni][reg];
      }
    }
}

// ---------------- CSR aggregation (wave-per-node, full 512-feat row) ----------------
// xrelu = relu(b + dinv_i^2*h_i + sum coef*h_src); h fp16 -> one 16B load per
// neighbor row per lane. Emit X as SINGLE fp16 stream (2-term GEMM split) +
// optional fp32 for the final conv. Plain 16B stores.

__global__ __launch_bounds__(256) void k_agg(const _Float16* __restrict__ h,
    _Float16* __restrict__ xhi, float* __restrict__ xf,
    const int* __restrict__ row_start, const int* __restrict__ csr_src,
    const float* __restrict__ csr_coef, const float* __restrict__ dinv,
    const float* __restrict__ bias) {
  int wid = threadIdx.x >> 6, lane = threadIdx.x & 63;
  int i = blockIdx.x * 4 + wid;
  if (i >= NN) return;
  int c = lane * 8;  // feats [c, c+8)
  float di = dinv[i];
  float d2 = di * di;
  half8 hv = *(const half8*)(h + (size_t)i * HDIM + c);
  f4 sA, sB;
  h8_to_f4(hv, sA, sB);
  f4 a0 = sA * d2, b0 = sB * d2;
  f4 z = {0.f, 0.f, 0.f, 0.f};
  f4 a1 = z, b1 = z, a2 = z, b2 = z, a3 = z, b3 = z;
  int e0 = row_start[i], e1 = row_start[i + 1];
  int e = e0;
  // 8 independent row-gathers (8 dwordx4 loads) in flight per wave
  for (; e + 8 <= e1; e += 8) {
    int s0 = csr_src[e], s1 = csr_src[e + 1], s2 = csr_src[e + 2], s3 = csr_src[e + 3];
    int s4 = csr_src[e + 4], s5 = csr_src[e + 5], s6 = csr_src[e + 6], s7 = csr_src[e + 7];
    float c0 = csr_coef[e], c1 = csr_coef[e + 1], c2 = csr_coef[e + 2], c3 = csr_coef[e + 3];
    float c4 = csr_coef[e + 4], c5 = csr_coef[e + 5], c6 = csr_coef[e + 6], c7 = csr_coef[e + 7];
    half8 r0 = *(const half8*)(h + (size_t)s0 * HDIM + c);
    half8 r1 = *(const half8*)(h + (size_t)s1 * HDIM + c);
    half8 r2 = *(const half8*)(h + (size_t)s2 * HDIM + c);
    half8 r3 = *(const half8*)(h + (size_t)s3 * HDIM + c);
    half8 r4 = *(const half8*)(h + (size_t)s4 * HDIM + c);
    half8 r5 = *(const half8*)(h + (size_t)s5 * HDIM + c);
    half8 r6 = *(const half8*)(h + (size_t)s6 * HDIM + c);
    half8 r7 = *(const half8*)(h + (size_t)s7 * HDIM + c);
    f4 pA, pB;
    h8_to_f4(r0, pA, pB); a0 += pA * c0; b0 += pB * c0;
    h8_to_f4(r1, pA, pB); a1 += pA * c1; b1 += pB * c1;
    h8_to_f4(r2, pA, pB); a2 += pA * c2; b2 += pB * c2;
    h8_to_f4(r3, pA, pB); a3 += pA * c3; b3 += pB * c3;
    h8_to_f4(r4, pA, pB); a0 += pA * c4; b0 += pB * c4;
    h8_to_f4(r5, pA, pB); a1 += pA * c5; b1 += pB * c5;
    h8_to_f4(r6, pA, pB); a2 += pA * c6; b2 += pB * c6;
    h8_to_f4(r7, pA, pB); a3 += pA * c7; b3 += pB * c7;
  }
  for (; e + 4 <= e1; e += 4) {
    int s0 = csr_src[e], s1 = csr_src[e + 1], s2 = csr_src[e + 2], s3 = csr_src[e + 3];
    float c0 = csr_coef[e], c1 = csr_coef[e + 1], c2 = csr_coef[e + 2], c3 = csr_coef[e + 3];
    half8 r0 = *(const half8*)(h + (size_t)s0 * HDIM + c);
    half8 r1 = *(const half8*)(h + (size_t)s1 * HDIM + c);
    half8 r2 = *(const half8*)(h + (size_t)s2 * HDIM + c);
    half8 r3 = *(const half8*)(h + (size_t)s3 * HDIM + c);
    f4 pA, pB;
    h8_to_f4(r0, pA, pB); a0 += pA * c0; b0 += pB * c0;
    h8_to_f4(r1, pA, pB); a1 += pA * c1; b1 += pB * c1;
    h8_to_f4(r2, pA, pB); a2 += pA * c2; b2 += pB * c2;
    h8_to_f4(r3, pA, pB); a3 += pA * c3; b3 += pB * c3;
  }
  for (; e < e1; ++e) {
    int s = csr_src[e];
    float cf = csr_coef[e];
    half8 r0 = *(const half8*)(h + (size_t)s * HDIM + c);
    f4 pA, pB;
    h8_to_f4(r0, pA, pB);
    a0 += pA * cf; b0 += pB * cf;
  }
  f4 accA = (a0 + a1) + (a2 + a3);
  f4 accB = (b0 + b1) + (b2 + b3);
  accA += *(const f4*)(bias + c);
  accB += *(const f4*)(bias + c + 4);
  half8 hh;
#pragma unroll
  for (int q = 0; q < 4; ++q) {
    accA[q] = fmaxf(accA[q], 0.f);
    accB[q] = fmaxf(accB[q], 0.f);
    hh[q] = (_Float16)accA[q];
    hh[q + 4] = (_Float16)accB[q];
  }
  *(half8*)(xhi + (size_t)i * HDIM + c) = hh;
  if (xf) {
    f4* xo = (f4*)(xf + (size_t)i * HDIM + c);
    xo[0] = accA;
    xo[1] = accB;
  }
}

// final conv: h3[N,3] = X[N,512] @ W1[512,3]; one wave per node
__global__ __launch_bounds__(256) void k_gemm3(const float* __restrict__ X, const float* __restrict__ W1,
    float* __restrict__ h3) {
  int wid = threadIdx.x >> 6, lane = threadIdx.x & 63;
  int i = blockIdx.x * 4 + wid;
  if (i >= NN) return;
  const float* xi = X + (size_t)i * HDIM;
  float a0 = 0.f, a1 = 0.f, a2 = 0.f;
#pragma unroll
  for (int t = 0; t < HDIM / 64; ++t) {
    int k = t * 64 + lane;
    float v = xi[k];
    a0 = fmaf(v, W1[k * 3 + 0], a0);
    a1 = fmaf(v, W1[k * 3 + 1], a1);
    a2 = fmaf(v, W1[k * 3 + 2], a2);
  }
#pragma unroll
  for (int off = 32; off > 0; off >>= 1) {
    a0 += __shfl_down(a0, off);
    a1 += __shfl_down(a1, off);
    a2 += __shfl_down(a2, off);
  }
  if (lane == 0) {
    h3[(size_t)i * 3 + 0] = a0;
    h3[(size_t)i * 3 + 1] = a1;
    h3[(size_t)i * 3 + 2] = a2;
  }
}

__global__ __launch_bounds__(256) void k_agg3(const float* __restrict__ h3, float* __restrict__ out,
    const int* __restrict__ row_start, const int* __restrict__ csr_src,
    const float* __restrict__ csr_coef, const float* __restrict__ dinv,
    const float* __restrict__ b1) {
  int i = blockIdx.x * 256 + threadIdx.x;
  if (i >= NN) return;
  float d2 = dinv[i] * dinv[i];
  float o0 = h3[(size_t)i * 3 + 0] * d2;
  float o1 = h3[(size_t)i * 3 + 1] * d2;
  float o2 = h3[(size_t)i * 3 + 2] * d2;
  int e0 = row_start[i], e1 = row_start[i + 1];
  for (int e = e0; e < e1; ++e) {
    int s = csr_src[e];
    float c = csr_coef[e];
    o0 = fmaf(c, h3[(size_t)s * 3 + 0], o0);
    o1 = fmaf(c, h3[(size_t)s * 3 + 1], o1);
    o2 = fmaf(c, h3[(size_t)s * 3 + 2], o2);
  }
  out[(size_t)i * 3 + 0] = o0 + b1[0];
  out[(size_t)i * 3 + 1] = o1 + b1[1];
  out[(size_t)i * 3 + 2] = o2 + b1[2];
}

// ---------------- launch ----------------

extern "C" void kernel_launch(void* const* d_in, const int* in_sizes, int n_in,
                              void* d_out, int out_size, void* d_ws, size_t ws_size,
                              hipStream_t stream) {
  const float* x  = (const float*)d_in[0];
  const int*   ei = (const int*)d_in[1];
  const float* W0 = (const float*)d_in[2];
  const float* b0 = (const float*)d_in[3];
  const float* Wr = (const float*)d_in[4];
  const float* br = (const float*)d_in[5];
  const float* W1 = (const float*)d_in[6];
  const float* b1 = (const float*)d_in[7];
  float* out = (float*)d_out;
  float* X = out + (size_t)NN * CDIM;  // final relu'd state [NN, HDIM] == output 1

  char* ws = (char*)d_ws;
  size_t off = 0;
  auto alloc = [&](size_t bytes) -> void* {
    void* p = ws + off;
    off = (off + bytes + 255) & ~(size_t)255;
    return p;
  };
  _Float16*  Yh     = (_Float16*)alloc((size_t)NN * HDIM * 2);     // 51.2 MB (fp16 Y)
  _Float16*  Xhi    = (_Float16*)alloc((size_t)NN * HDIM * 2);     // 51.2 MB
  _Float16*  W0thi  = (_Float16*)alloc((size_t)FDIM * HDIM * 2);
  _Float16*  W0tlo  = (_Float16*)alloc((size_t)FDIM * HDIM * 2);
  _Float16*  Wrthi  = (_Float16*)alloc((size_t)NBLK * 2 * HDIM * HDIM * 2);
  _Float16*  Wrtlo  = (_Float16*)alloc((size_t)NBLK * 2 * HDIM * HDIM * 2);
  float*     csr_coef = (float*)alloc((size_t)NE * 4);
  float*     dinv     = (float*)alloc((size_t)NN * 4);
  float*     h3       = (float*)alloc((size_t)NN * CDIM * 4);
  int*       cnt      = (int*)alloc((size_t)NN * 4);
  int*       fill     = (int*)alloc((size_t)NN * 4);
  int*       row_start= (int*)alloc((size_t)(NN + 1) * 4);
  int*       csr_src  = (int*)alloc((size_t)NE * 4);

  const int* src = ei;
  const int* dst = ei + NE;

  // ---- setup (once per call; reused by all 14 layers) ----
  k_zero_i32<<<(NN + 255) / 256, 256, 0, stream>>>(cnt, NN);
  k_zero_i32<<<(NN + 255) / 256, 256, 0, stream>>>(fill, NN);
  k_hist<<<(NE + 255) / 256, 256, 0, stream>>>(dst, cnt);
  k_dinv<<<(NN + 255) / 256, 256, 0, stream>>>(cnt, dinv);
  k_scan<<<1, 1024, 0, stream>>>(cnt, row_start);
  k_fill<<<(NE + 255) / 256, 256, 0, stream>>>(src, dst, row_start, fill, dinv, csr_src, csr_coef);

  // weight + input conversion (A single fp16; weights hi/lo, transposed to [N][K])
  k_cvt_x<<<(NN * FDIM / 4 + 255) / 256, 256, 0, stream>>>(x, Xhi, NN * FDIM / 4);
  {
    dim3 g0(FDIM / 32, HDIM / 32, 1);
    k_cvt_wt<<<g0, 256, 0, stream>>>(W0, W0thi, W0tlo, FDIM, HDIM);
    dim3 gr(HDIM / 32, HDIM / 32, NBLK * 2);
    k_cvt_wt<<<gr, 256, 0, stream>>>(Wr, Wrthi, Wrtlo, HDIM, HDIM);
  }

  const int nrb = (NN + 127) / 128;          // 391 row blocks
  const int rpx = (nrb + 7) / 8;             // 49 per XCD
  const int gemm_blocks = 8 * rpx * 4;       // 1568 (XCD-swizzled 1D grid)
  dim3 agg_grid((NN + 3) / 4);               // wave per node, full 512 feats

  // conv0: (x0 fp16 lives in the head of Xhi; consumed before agg overwrites)
  k_gemm16<<<gemm_blocks, 256, 0, stream>>>(Xhi, W0thi, W0tlo, Yh, NN, FDIM);
  k_agg<<<agg_grid, 256, 0, stream>>>(Yh, Xhi, nullptr, row_start, csr_src, csr_coef, dinv, b0);

  // 6 residual blocks x 2 convs, all H->H
  for (int ib = 0; ib < NBLK; ++ib) {
    for (int j = 0; j < 2; ++j) {
      int li = ib * 2 + j;
      const _Float16* Wh = Wrthi + (size_t)li * HDIM * HDIM;
      const _Float16* Wl = Wrtlo + (size_t)li * HDIM * HDIM;
      const float* bb = br + (size_t)li * HDIM;
      bool last = (ib == NBLK - 1) && (j == 1);
      k_gemm16<<<gemm_blocks, 256, 0, stream>>>(Xhi, Wh, Wl, Yh, NN, HDIM);
      k_agg<<<agg_grid, 256, 0, stream>>>(Yh, Xhi, last ? X : nullptr,
                                          row_start, csr_src, csr_coef, dinv, bb);
    }
  }

  // final conv: X (relu'd, fp32) @ W1 -> out[N,3]
  k_gemm3<<<(NN + 3) / 4, 256, 0, stream>>>(X, W1, h3);
  k_agg3<<<(NN + 255) / 256, 256, 0, stream>>>(h3, out, row_start, csr_src, csr_coef, dinv, b1);
}